// Round 10
// baseline (42.642 us; speedup 1.0000x reference)
//
#include <hip/hip_runtime.h>

#define BATCH 16
#define NN 1000
#define DD 256
#define KMAX 512

#define META_STRIDE 2560   // ints per batch: inv1[1000], inv2[1000], order[512], U
#define AP 1024            // row stride (elements) of adjb(u8) and T(u8)

typedef unsigned char u8;
typedef __attribute__((ext_vector_type(4))) int i32x4;

#define LD4(p) (*(const float4*)(p))

// ---------------- meta body ----------------
__device__ __forceinline__ void meta_body(
    int b, int t,
    const int* __restrict__ idx1, const int* __restrict__ idx2,
    const int* __restrict__ k1, const int* __restrict__ k2,
    int* __restrict__ meta, int* sc, int* sU) {
  int* inv1 = meta + (size_t)b * META_STRIDE;
  int* inv2 = inv1 + NN;
  int* order = inv2 + NN;
  int* Uptr = order + KMAX;
  const int* i1 = idx1 + (size_t)b * NN;
  const int* i2 = idx2 + (size_t)b * NN;
  for (int j = t; j < NN; j += 256) {
    inv1[i1[j]] = j;
    inv2[i2[j]] = j;
  }
  __syncthreads();
  int kk1 = k1[b], kk2 = k2[b];
  int base = t * 4;
  int un[4];
  int cnt = 0;
  for (int i = 0; i < 4; ++i) {
    int v = base + i;
    int u = 0;
    if (v < NN) u = (inv1[v] < kk1) || (inv2[v] < kk2);
    un[i] = u;
    cnt += u;
  }
  sc[t] = cnt;
  __syncthreads();
  for (int off = 1; off < 256; off <<= 1) {
    int v = (t >= off) ? sc[t - off] : 0;
    __syncthreads();
    sc[t] += v;
    __syncthreads();
  }
  int pref = sc[t] - cnt;
  for (int i = 0; i < 4; ++i)
    if (un[i]) order[pref++] = base + i;
  if (t == 255) {
    *sU = sc[255];
    *Uptr = sc[255];
  }
  __syncthreads();
  int U = *sU;
  for (int r = U + t; r < KMAX; r += 256) order[r] = 0;  // safe gather index
}

__global__ __launch_bounds__(256) void meta_kernel(
    const int* __restrict__ idx1, const int* __restrict__ idx2,
    const int* __restrict__ k1, const int* __restrict__ k2,
    int* __restrict__ meta) {
  __shared__ int sc[256];
  __shared__ int sU;
  meta_body(blockIdx.x, threadIdx.x, idx1, idx2, k1, k2, meta, sc, &sU);
}

// ---------------- fp32 -> u8 pack ----------------
__device__ __forceinline__ unsigned int pack4u8(float4 f) {
  return (unsigned int)(u8)f.x | ((unsigned int)(u8)f.y << 8) |
         ((unsigned int)(u8)f.z << 16) | ((unsigned int)(u8)f.w << 24);
}

// conv body: 4 rows/block, 64 lanes/row, contiguous float4 loads (coalesced)
__device__ __forceinline__ void conv_rows(
    const float* __restrict__ adj, u8* __restrict__ adjb,
    int b_src, int b_dst, int r, int l) {
  const float* srcrow = adj + ((size_t)b_src * NN + r) * NN;
  u8* dstrow = adjb + ((size_t)b_dst * AP + r) * AP;
#pragma unroll
  for (int j = 0; j < 4; ++j) {
    int idx = l + 64 * j;            // float4 index, 0..255
    unsigned int w = 0;
    if (r < NN && idx < 250) w = pack4u8(LD4(srcrow + idx * 4));
    *(unsigned int*)(dstrow + idx * 4) = w;
  }
}

// fallback conv (non-pinned, chunked)
__global__ __launch_bounds__(256) void conv_fb_kernel(
    const float* __restrict__ adj, u8* __restrict__ adjb, int bbase) {
  int bz = blockIdx.y;
  int tid = threadIdx.x;
  int r = blockIdx.x * 4 + (tid >> 6);
  conv_rows(adj, adjb, bbase + bz, bz, r, tid & 63);
}

// ---------------- feat: one output row (64 lanes, float4 each) ----------------
__device__ __forceinline__ void feat_row(
    const float* __restrict__ H1, const float* __restrict__ H2,
    const int* __restrict__ k1, const int* __restrict__ k2,
    const int* __restrict__ meta, float* __restrict__ outH,
    float* __restrict__ outMask, int b, int r, int l) {
  const int* inv1 = meta + (size_t)b * META_STRIDE;
  const int* inv2 = inv1 + NN;
  const int* order = inv2 + NN;
  int U = order[KMAX];
  float4* oH = (float4*)(outH + ((size_t)b * KMAX + r) * DD) + l;
  if (r >= U) {
    *oH = make_float4(0.f, 0.f, 0.f, 0.f);
    if (l == 0) outMask[(size_t)b * KMAX + r] = 0.f;
    return;
  }
  int v = order[r];
  int j1 = inv1[v];
  int j2 = inv2[v];
  bool in1 = j1 < k1[b];
  bool in2 = j2 < k2[b];
  const float4* h1 = (const float4*)(H1 + ((size_t)b * NN + j1) * DD) + l;
  const float4* h2 = (const float4*)(H2 + ((size_t)b * NN + j2) * DD) + l;
  float4 o;
  if (in1 && in2) {
    float4 a = *h1, c = *h2;
    o = make_float4(0.5f * (a.x + c.x), 0.5f * (a.y + c.y),
                    0.5f * (a.z + c.z), 0.5f * (a.w + c.w));
  } else if (in1) {
    o = *h1;
  } else {
    o = *h2;
  }
  *oH = o;
  if (l == 0) outMask[(size_t)b * KMAX + r] = 1.f;
}

__global__ __launch_bounds__(256) void feat_kernel(
    const float* __restrict__ H1, const float* __restrict__ H2,
    const int* __restrict__ k1, const int* __restrict__ k2,
    const int* __restrict__ meta,
    float* __restrict__ outH, float* __restrict__ outMask, int bbase) {
  int tid = threadIdx.x;
  int r = blockIdx.x * 4 + (tid >> 6);
  int b = blockIdx.y + bbase;
  feat_row(H1, H2, k1, k2, meta, outH, outMask, b, r, tid & 63);
}

// ---------------- mm tile body: i8 MFMA, BK=128, counted-vmcnt dbuf ----------------
// WHICH==1: T[512][1024](u8) = gather(adjb, order) @ adjb      (BM=64, BN=128)
// WHICH==2: outAdj[512][512](f32) = T @ gather(adjb, order)^T  (BM=BN=64)
template<int WHICH>
__device__ __forceinline__ void mm_tile(
    const u8* __restrict__ adjbB, u8* __restrict__ TbB,
    const int* __restrict__ order, float* __restrict__ outAdjB,
    int rt, int ct, int tid,
    u8* A0, u8* B0, u8* A1, u8* B1, int* sOrd) {
  constexpr int BM = 64;
  constexpr int BN = (WHICH == 1) ? 128 : 64;
  constexpr int MR = 2;
  constexpr int NR = BN / 32;                 // 4 or 2
  constexpr int LA = 2;
  constexpr int LB = (BN / 64) * 2;           // 4 or 2
  constexpr int LL = LA + LB;                 // 6 or 4
  constexpr int NKT = AP / 128;               // 8

  int U = order[KMAX];
  int lane = tid & 63;
  int w = tid >> 6;
  int wr = w >> 1, wc = w & 1;

  bool active;
  if (WHICH == 1) {
    active = (rt * BM < U);
    if (!active) return;  // rows never consumed downstream
  } else {
    active = (rt * BM < U) && (ct * BN < U);
  }

  if (tid < 64) sOrd[tid] = order[((WHICH == 1) ? rt * BM : ct * BN) + tid];
  __syncthreads();

  i32x4 acc[MR][NR] = {};

#define WAITV(N) asm volatile("s_waitcnt vmcnt(%0)" :: "i"(N) : "memory")
#define BARx() do { asm volatile("" ::: "memory"); __builtin_amdgcn_s_barrier(); \
                    asm volatile("" ::: "memory"); } while (0)

#define STAGE(ABUF, BBUF, KT)                                                  \
  {                                                                            \
    int k0 = (KT) * 128;                                                       \
    _Pragma("unroll")                                                          \
    for (int i = 0; i < LA; ++i) {                                             \
      int p = i * 256 + tid;                                                   \
      int r = p >> 3, cp = p & 7;                                              \
      int cs = cp ^ (r & 7);                                                   \
      const u8* src = (WHICH == 1)                                             \
          ? adjbB + (size_t)sOrd[r] * AP + k0 + cs * 16                        \
          : TbB + (size_t)(rt * BM + r) * AP + k0 + cs * 16;                   \
      u8* dst = (ABUF) + (size_t)(i * 256 + (tid & 192)) * 16;                 \
      __builtin_amdgcn_global_load_lds(                                        \
          (const __attribute__((address_space(1))) void*)src,                  \
          (__attribute__((address_space(3))) void*)dst, 16, 0, 0);             \
    }                                                                          \
    _Pragma("unroll")                                                          \
    for (int i = 0; i < LB; ++i) {                                             \
      int p = i * 256 + tid;                                                   \
      int r = p >> 3, cp = p & 7;                                              \
      int cs = cp ^ (r & 7);                                                   \
      const u8* src = (WHICH == 1)                                             \
          ? adjbB + (size_t)(ct * BN + r) * AP + k0 + cs * 16                  \
          : adjbB + (size_t)sOrd[r] * AP + k0 + cs * 16;                       \
      u8* dst = (BBUF) + (size_t)(i * 256 + (tid & 192)) * 16;                 \
      __builtin_amdgcn_global_load_lds(                                        \
          (const __attribute__((address_space(1))) void*)src,                  \
          (__attribute__((address_space(3))) void*)dst, 16, 0, 0);             \
    }                                                                          \
  }

#define COMPUTE128(ABUF, BBUF)                                                 \
  {                                                                            \
    _Pragma("unroll")                                                          \
    for (int s = 0; s < 2; ++s) {                                              \
      i32x4 a[MR], bv[NR];                                                     \
      _Pragma("unroll")                                                        \
      for (int m = 0; m < MR; ++m) {                                           \
        int row = wr * (MR * 16) + m * 16 + (lane & 15);                       \
        int c = (s * 4 + (lane >> 4)) ^ (row & 7);                             \
        a[m] = *(const i32x4*)((ABUF) + row * 128 + c * 16);                   \
      }                                                                        \
      _Pragma("unroll")                                                        \
      for (int n = 0; n < NR; ++n) {                                           \
        int row = wc * (NR * 16) + n * 16 + (lane & 15);                       \
        int c = (s * 4 + (lane >> 4)) ^ (row & 7);                             \
        bv[n] = *(const i32x4*)((BBUF) + row * 128 + c * 16);                  \
      }                                                                        \
      __builtin_amdgcn_s_setprio(1);                                           \
      _Pragma("unroll")                                                        \
      for (int m = 0; m < MR; ++m)                                             \
        _Pragma("unroll")                                                      \
        for (int n = 0; n < NR; ++n)                                           \
          acc[m][n] = __builtin_amdgcn_mfma_i32_16x16x64_i8(a[m], bv[n],       \
                                                            acc[m][n], 0, 0, 0); \
      __builtin_amdgcn_s_setprio(0);                                           \
    }                                                                          \
  }

  if (active) {
    STAGE(A0, B0, 0);
    STAGE(A1, B1, 1);
#pragma unroll 1
    for (int t = 0; t < NKT - 2; t += 2) {
      WAITV(LL);            // own tile-t loads done (t+1 still in flight)
      BARx();               // all waves' tile-t data landed
      COMPUTE128(A0, B0);
      BARx();               // all waves done reading A0/B0
      STAGE(A0, B0, t + 2);
      WAITV(LL);
      BARx();
      COMPUTE128(A1, B1);
      BARx();
      STAGE(A1, B1, t + 3);
    }
    WAITV(LL);
    BARx();
    COMPUTE128(A0, B0);     // tile NKT-2
    WAITV(0);
    BARx();
    COMPUTE128(A1, B1);     // tile NKT-1
  }
#undef STAGE
#undef COMPUTE128
#undef WAITV
#undef BARx

  // ---- epilogue ----
  if (WHICH == 1) {
#pragma unroll
    for (int m = 0; m < MR; ++m)
#pragma unroll
      for (int n = 0; n < NR; ++n)
#pragma unroll
        for (int i = 0; i < 4; ++i) {
          int row = rt * BM + wr * (MR * 16) + m * 16 + ((lane >> 4) << 2) + i;
          int col = ct * BN + wc * (NR * 16) + n * 16 + (lane & 15);
          TbB[(size_t)row * AP + col] = (u8)acc[m][n][i];
        }
  } else {
#pragma unroll
    for (int m = 0; m < MR; ++m)
#pragma unroll
      for (int n = 0; n < NR; ++n)
#pragma unroll
        for (int i = 0; i < 4; ++i) {
          int row = rt * BM + wr * (MR * 16) + m * 16 + ((lane >> 4) << 2) + i;
          int col = ct * BN + wc * (NR * 16) + n * 16 + (lane & 15);
          float v = (row < U && col < U) ? (float)acc[m][n][i] : 0.f;
          outAdjB[(size_t)row * KMAX + col] = v;
        }
  }
}

// ---------------- fused role-dispatch kernel ----------------
// block ranges (all multiples of 8): [mm1N*64) mm1 | [mm2N*64) mm2 |
// [convN*256) conv | [featN*64) feat | [metaN) meta.
// Pinning: batch -> XCD b%8 via (section-local idx & 7).
__global__ __launch_bounds__(256) void fused_kernel(
    const float* __restrict__ adj, u8* __restrict__ adjb, u8* __restrict__ Tb,
    int* __restrict__ meta, float* __restrict__ outAdj,
    const float* __restrict__ H1, const float* __restrict__ H2,
    const int* __restrict__ idx1, const int* __restrict__ idx2,
    const int* __restrict__ k1, const int* __restrict__ k2,
    float* __restrict__ outH, float* __restrict__ outMask,
    int mm1N, int mm1B0, int mm2N, int mm2B0,
    int convN, int convB0, int featN, int metaN) {
  __shared__ __align__(16) u8 smem[49408];
  u8* A0 = smem;
  u8* A1 = smem + 8192;
  u8* B0 = smem + 16384;
  u8* B1 = smem + 32768;
  int* sOrd = (int*)(smem + 49152);

  int g = blockIdx.x;
  int tid = threadIdx.x;

  int s_mm1 = mm1N * 64;
  if (g < s_mm1) {
    int b = mm1B0 + (g & 7);
    int tile = g >> 3;
    int rt = tile >> 3, ct = tile & 7;
    mm_tile<1>(adjb + (size_t)b * AP * AP, Tb + (size_t)b * KMAX * AP,
               meta + (size_t)b * META_STRIDE + 2 * NN,
               nullptr, rt, ct, tid, A0, B0, A1, B1, sOrd);
    return;
  }
  g -= s_mm1;
  int s_mm2 = mm2N * 64;
  if (g < s_mm2) {
    int b = mm2B0 + (g & 7);
    int tile = g >> 3;
    int rt = tile >> 3, ct = tile & 7;
    mm_tile<2>(adjb + (size_t)b * AP * AP, Tb + (size_t)b * KMAX * AP,
               meta + (size_t)b * META_STRIDE + 2 * NN,
               outAdj + (size_t)b * KMAX * KMAX, rt, ct, tid, A0, B0, A1, B1, sOrd);
    return;
  }
  g -= s_mm2;
  int s_conv = convN * 256;
  if (g < s_conv) {
    int b = convB0 + (g & 7);
    int slot = g >> 3;                 // 0..255
    int r = slot * 4 + (tid >> 6);
    conv_rows(adj, adjb, b, b, r, tid & 63);
    return;
  }
  g -= s_conv;
  int s_feat = featN * 64;
  if (g < s_feat) {
    int xcd = g & 7;
    int slot = g >> 3;                 // 0..127
    int b = xcd + 8 * (slot >> 6);
    int rb = slot & 63;
    int l = tid & 63;
#pragma unroll
    for (int pass = 0; pass < 2; ++pass) {
      int r = rb * 8 + pass * 4 + (tid >> 6);
      feat_row(H1, H2, k1, k2, meta, outH, outMask, b, r, l);
    }
    return;
  }
  g -= s_feat;
  if (g < metaN) {
    meta_body(g, tid, idx1, idx2, k1, k2, meta, (int*)smem, (int*)(smem + 1024));
  }
}

// ---------------- fallback mm kernel (non-pinned, chunked ws) ----------------
template<int WHICH>
__global__ __launch_bounds__(256) void mm_fb_kernel(
    const u8* __restrict__ adjb, u8* __restrict__ Tb,
    const int* __restrict__ meta, float* __restrict__ outAdj, int bbase) {
  __shared__ __align__(16) u8 smem[49408];
  u8* A0 = smem;
  u8* A1 = smem + 8192;
  u8* B0 = smem + 16384;
  u8* B1 = smem + 32768;
  int* sOrd = (int*)(smem + 49152);
  int bz = blockIdx.z;
  int b = bbase + bz;
  mm_tile<WHICH>(adjb + (size_t)bz * AP * AP, Tb + (size_t)bz * KMAX * AP,
                 meta + (size_t)b * META_STRIDE + 2 * NN,
                 outAdj + (size_t)b * KMAX * KMAX,
                 blockIdx.y, blockIdx.x, threadIdx.x, A0, B0, A1, B1, sOrd);
}

extern "C" void kernel_launch(void* const* d_in, const int* in_sizes, int n_in,
                              void* d_out, int out_size, void* d_ws, size_t ws_size,
                              hipStream_t stream) {
  const float* adj = (const float*)d_in[0];
  const float* H1 = (const float*)d_in[1];
  const float* H2 = (const float*)d_in[2];
  const int* idx1 = (const int*)d_in[3];
  const int* idx2 = (const int*)d_in[4];
  const int* k1 = (const int*)d_in[5];
  const int* k2 = (const int*)d_in[6];

  float* outH = (float*)d_out;                              // [B,KMAX,DD]
  float* outAdj = outH + (size_t)BATCH * KMAX * DD;         // [B,KMAX,KMAX]
  float* outMask = outAdj + (size_t)BATCH * KMAX * KMAX;    // [B,KMAX]

  int* meta = (int*)d_ws;
  size_t meta_bytes = (size_t)BATCH * META_STRIDE * sizeof(int);
  size_t meta_al = (meta_bytes + 255) & ~(size_t)255;

  size_t adjb_one = (size_t)AP * AP;          // 1 MB (u8)
  size_t T_one = (size_t)KMAX * AP;           // 512 KB (u8)
  size_t per_b = adjb_one + T_one;            // 1.5 MB

  int chunk = 1;
  if (ws_size > meta_al + per_b)
    chunk = (int)((ws_size - meta_al) / per_b);
  if (chunk > BATCH) chunk = BATCH;
  if (chunk < 1) chunk = 1;

  u8* adjb = (u8*)((char*)d_ws + meta_al);
  u8* Tb = adjb + (size_t)chunk * adjb_one;

  if (chunk == BATCH) {
    // Pipelined phases at half-batch granularity:
    // L1: conv(0-7) + meta(all)
    fused_kernel<<<dim3(8 * 256 + 16), 256, 0, stream>>>(
        adj, adjb, Tb, meta, outAdj, H1, H2, idx1, idx2, k1, k2, outH, outMask,
        0, 0, 0, 0, 8, 0, 0, 16);
    // L2: mm1(0-7) || conv(8-15)
    fused_kernel<<<dim3(8 * 64 + 8 * 256), 256, 0, stream>>>(
        adj, adjb, Tb, meta, outAdj, H1, H2, idx1, idx2, k1, k2, outH, outMask,
        8, 0, 0, 0, 8, 8, 0, 0);
    // L3: mm1(8-15) || mm2(0-7) || feat(all)
    fused_kernel<<<dim3(8 * 64 + 8 * 64 + 16 * 64), 256, 0, stream>>>(
        adj, adjb, Tb, meta, outAdj, H1, H2, idx1, idx2, k1, k2, outH, outMask,
        8, 8, 8, 0, 0, 0, 16, 0);
    // L4: mm2(8-15)
    fused_kernel<<<dim3(8 * 64), 256, 0, stream>>>(
        adj, adjb, Tb, meta, outAdj, H1, H2, idx1, idx2, k1, k2, outH, outMask,
        0, 0, 8, 8, 0, 0, 0, 0);
  } else {
    meta_kernel<<<dim3(BATCH), 256, 0, stream>>>(idx1, idx2, k1, k2, meta);
    feat_kernel<<<dim3(KMAX / 4, BATCH), 256, 0, stream>>>(H1, H2, k1, k2, meta,
                                                           outH, outMask, 0);
    for (int bb = 0; bb < BATCH; bb += chunk) {
      int nb = (BATCH - bb < chunk) ? (BATCH - bb) : chunk;
      conv_fb_kernel<<<dim3(256, nb), 256, 0, stream>>>(adj, adjb, bb);
      mm_fb_kernel<1><<<dim3(8, 8, nb), 256, 0, stream>>>(adjb, Tb, meta, outAdj, bb);
      mm_fb_kernel<2><<<dim3(8, 8, nb), 256, 0, stream>>>(adjb, Tb, meta, outAdj, bb);
    }
  }
}